// Round 5
// baseline (370.550 us; speedup 1.0000x reference)
//
#include <hip/hip_runtime.h>
#include <hip/hip_bf16.h>

// SparseGAT forward. fp16-MFMA feature transform; CSR-fused edge pipeline.
// N=50000, FI=256, FO=64, H=8, E=800000.
//
// Th  [n][h*64+f]  head-major (K1 output, coalesced MFMA epilogue)
// Th2 [n][f*8+h]   head-minor (k4 gather: 1 x b128 per edge per lane)
//
// ws: Th[N*512]f16 | Th2[N*512]f16 | Wth[8*64*256]f16 | aw[N*8]f32
//     | deg[N] | row_start[N+4] | cursor[N] | colperm[E] | blocksums[64]

#define FI 256
#define FO 64
#define NH 8
#define FC (NH * FO)  // 512

typedef _Float16 f16x8 __attribute__((ext_vector_type(8)));
typedef float f32x16 __attribute__((ext_vector_type(16)));
typedef float f32x8 __attribute__((ext_vector_type(8)));

// ---------------- P1: W[h][k][f] -> Wth[h][f][k] fp16 -----------------------
__global__ __launch_bounds__(256)
void p1_wconv(const float* __restrict__ W, _Float16* __restrict__ Wth) {
  int idx = blockIdx.x * 256 + threadIdx.x;   // h*64*256 + f*256 + k
  if (idx >= NH * FO * FI) return;
  int k = idx & (FI - 1);
  int f = (idx >> 8) & (FO - 1);
  int h = idx >> 14;
  Wth[idx] = (_Float16)W[((size_t)h * FI + k) * FO + f];
}

// ---------------- K1: T = x @ W per head, fp16 MFMA (fp32->fp16 fused) ------
__global__ __launch_bounds__(256)
void k1_mfma(const float* __restrict__ x, const _Float16* __restrict__ Wth,
             _Float16* __restrict__ Th, int N) {
  __shared__ _Float16 Xs[64][264];
  const int h   = blockIdx.y;
  const int bm  = blockIdx.x * 64;
  const int t   = threadIdx.x;
  const int lane = t & 63;
  const int wid  = t >> 6;
  const int wr = wid >> 1, wc = wid & 1;

  // stage 64x256 x-tile: load fp32 float4, convert to fp16, store 8B to LDS
  #pragma unroll
  for (int r = 0; r < 16; ++r) {
    int i = t + r * 256;            // float4 chunk 0..4095
    int row = i >> 6;               // 64 float4 per row
    int q   = i & 63;
    int grow = bm + row;
    float4 v = make_float4(0.f, 0.f, 0.f, 0.f);
    if (grow < N)
      v = reinterpret_cast<const float4*>(&x[(size_t)grow * FI])[q];
    _Float16 o[4] = {(_Float16)v.x, (_Float16)v.y, (_Float16)v.z, (_Float16)v.w};
    *reinterpret_cast<uint2*>(&Xs[row][q * 4]) = *reinterpret_cast<uint2*>(o);
  }
  __syncthreads();

  const int l31 = lane & 31;
  const int kh  = (lane >> 5) * 8;
  const _Float16* Wcol = Wth + ((size_t)h * FO + wc * 32 + l31) * FI;
  const int arow = wr * 32 + l31;

  f32x16 acc = (f32x16)0.0f;
  #pragma unroll
  for (int kk = 0; kk < 16; ++kk) {
    f16x8 af = *reinterpret_cast<const f16x8*>(&Xs[arow][kk * 16 + kh]);
    f16x8 bf = *reinterpret_cast<const f16x8*>(&Wcol[kk * 16 + kh]);
    acc = __builtin_amdgcn_mfma_f32_32x32x16_f16(af, bf, acc, 0, 0, 0);
  }

  const int cbase = h * FO + wc * 32 + l31;
  #pragma unroll
  for (int reg = 0; reg < 16; ++reg) {
    int rr = (reg & 3) + 8 * (reg >> 2) + 4 * (lane >> 5);
    int grow = bm + wr * 32 + rr;
    if (grow < N) Th[(size_t)grow * FC + cbase] = (_Float16)acc[reg];
  }
}

// ---------------- K2T: aw[n,h] = dot(T[n,h,:], a[h]);  Th -> Th2 ------------
// 512 threads = 8 waves; wave w = head w, lane = feature f.
__global__ __launch_bounds__(512)
void k2t(const _Float16* __restrict__ Th, const float* __restrict__ a,
         float* __restrict__ aw, _Float16* __restrict__ Th2, int N) {
  __shared__ _Float16 buf[FC];
  const int n = blockIdx.x;
  const int w = threadIdx.x >> 6;
  const int lane = threadIdx.x & 63;
  _Float16 th = Th[(size_t)n * FC + w * FO + lane];
  buf[lane * NH + w] = th;              // transpose in LDS
  float v = (float)th * a[w * FO + lane];
  #pragma unroll
  for (int off = 32; off; off >>= 1) v += __shfl_down(v, off);
  if (lane == 0) aw[n * NH + w] = v;
  __syncthreads();
  // coalesced 16B store of transposed row by first 64 threads
  if (threadIdx.x < 64)
    reinterpret_cast<uint4*>(&Th2[(size_t)n * FC])[threadIdx.x] =
        reinterpret_cast<const uint4*>(buf)[threadIdx.x];
}

// ---------------- B1: degree histogram --------------------------------------
__global__ __launch_bounds__(256)
void b1_hist(const int* __restrict__ rows, int* __restrict__ deg, int E) {
  int e = blockIdx.x * 256 + threadIdx.x;
  if (e < E) atomicAdd(&deg[rows[e]], 1);
}

// ---------------- B2a: per-block sums (1024 elems/block) --------------------
__global__ __launch_bounds__(256)
void b2a_blocksum(const int* __restrict__ deg, int* __restrict__ blocksums, int N) {
  __shared__ int red[256];
  const int t = threadIdx.x;
  const int base = blockIdx.x * 1024 + t * 4;
  int s = 0;
  #pragma unroll
  for (int j = 0; j < 4; ++j) { int i = base + j; if (i < N) s += deg[i]; }
  red[t] = s;
  __syncthreads();
  for (int off = 128; off; off >>= 1) {
    if (t < off) red[t] += red[t + off];
    __syncthreads();
  }
  if (t == 0) blocksums[blockIdx.x] = red[0];
}

// ---------------- B2b: exclusive scan of block sums (1 wave) ----------------
__global__ __launch_bounds__(64)
void b2b_scanblocks(int* __restrict__ blocksums, int nb,
                    int* __restrict__ row_start, int N, int E) {
  const int lane = threadIdx.x;
  int carry = 0;
  for (int base = 0; base < nb; base += 64) {
    int i = base + lane;
    int v = (i < nb) ? blocksums[i] : 0;
    int inc = v;
    #pragma unroll
    for (int off = 1; off < 64; off <<= 1) {
      int t = __shfl_up(inc, off);
      if (lane >= off) inc += t;
    }
    if (i < nb) blocksums[i] = inc - v + carry;  // exclusive
    carry += __shfl(inc, 63);
  }
  if (lane == 0) row_start[N] = E;
}

// ---------------- B2c: per-block rescan -> row_start, cursor ----------------
__global__ __launch_bounds__(256)
void b2c_rescan(const int* __restrict__ deg, const int* __restrict__ blocksums,
                int* __restrict__ row_start, int* __restrict__ cursor, int N) {
  __shared__ int ts[256];
  const int t = threadIdx.x;
  const int base = blockIdx.x * 1024 + t * 4;
  int v[4]; int s = 0;
  #pragma unroll
  for (int j = 0; j < 4; ++j) { int i = base + j; v[j] = (i < N) ? deg[i] : 0; s += v[j]; }
  ts[t] = s;
  __syncthreads();
  for (int off = 1; off < 256; off <<= 1) {
    int add = (t >= off) ? ts[t - off] : 0;
    __syncthreads();
    ts[t] += add;
    __syncthreads();
  }
  int run = blocksums[blockIdx.x] + ts[t] - s;
  #pragma unroll
  for (int j = 0; j < 4; ++j) {
    int i = base + j;
    if (i < N) { row_start[i] = run; cursor[i] = run; run += v[j]; }
  }
}

// ---------------- B3: scatter cols into CSR order ---------------------------
__global__ __launch_bounds__(256)
void b3_scatter(const int* __restrict__ rows, const int* __restrict__ cols,
                int* __restrict__ cursor, int* __restrict__ colperm, int E) {
  int e = blockIdx.x * 256 + threadIdx.x;
  if (e >= E) return;
  int pos = atomicAdd(&cursor[rows[e]], 1);
  colperm[pos] = cols[e];
}

// ---------------- K4: fused softmax + aggregation + bias + relu -------------
// one wave per row; gather from Th2 = 1 x b128 per edge per lane.
__global__ __launch_bounds__(256)
void k4_fused(const int* __restrict__ row_start, const int* __restrict__ colperm,
              const float* __restrict__ aw, const _Float16* __restrict__ Th2,
              const float* __restrict__ b, float* __restrict__ out, int N) {
  const int lane = threadIdx.x & 63;
  const int r = blockIdx.x * 4 + (threadIdx.x >> 6);
  if (r >= N) return;

  const int s0 = row_start[r], s1 = row_start[r + 1];

  f32x8 awr = *reinterpret_cast<const f32x8*>(&aw[(size_t)r * NH]);

  float facc[NH] = {};
  float dacc[NH] = {};

  for (int base = s0; base < s1; base += 64) {
    const int m = min(64, s1 - base);
    const bool valid = lane < m;
    int c_l = valid ? colperm[base + lane] : 0;

    // lane-parallel: ex for this lane's edge (invalid lanes carry 0)
    f32x8 awc = *reinterpret_cast<const f32x8*>(&aw[(size_t)c_l * NH]);
    float ex[NH];
    #pragma unroll
    for (int h = 0; h < NH; ++h) {
      float s = awr[h] + awc[h];
      float lr = s > 0.f ? s : 0.2f * s;
      ex[h] = valid ? __expf(lr) : 0.f;
      dacc[h] += ex[h];
    }

    // serial over edges, 4 gathers in flight; lanes >= m carry ex=0/c=0
    for (int j = 0; j < m; j += 4) {
      int cj0 = __shfl(c_l, j);
      int cj1 = __shfl(c_l, j + 1);
      int cj2 = __shfl(c_l, j + 2);
      int cj3 = __shfl(c_l, j + 3);
      f16x8 tv0 = *reinterpret_cast<const f16x8*>(Th2 + (size_t)cj0 * FC + lane * NH);
      f16x8 tv1 = *reinterpret_cast<const f16x8*>(Th2 + (size_t)cj1 * FC + lane * NH);
      f16x8 tv2 = *reinterpret_cast<const f16x8*>(Th2 + (size_t)cj2 * FC + lane * NH);
      f16x8 tv3 = *reinterpret_cast<const f16x8*>(Th2 + (size_t)cj3 * FC + lane * NH);
      #pragma unroll
      for (int h = 0; h < NH; ++h) {
        facc[h] = fmaf(__shfl(ex[h], j),     (float)tv0[h], facc[h]);
        facc[h] = fmaf(__shfl(ex[h], j + 1), (float)tv1[h], facc[h]);
        facc[h] = fmaf(__shfl(ex[h], j + 2), (float)tv2[h], facc[h]);
        facc[h] = fmaf(__shfl(ex[h], j + 3), (float)tv3[h], facc[h]);
      }
    }
  }

  #pragma unroll
  for (int h = 0; h < NH; ++h) {
    #pragma unroll
    for (int off = 1; off < 64; off <<= 1)
      dacc[h] += __shfl_xor(dacc[h], off);
  }

  float sb = 0.f;
  #pragma unroll
  for (int h = 0; h < NH; ++h) sb += b[h * FO + lane];

  float v = 0.f;
  #pragma unroll
  for (int h = 0; h < NH; ++h) {
    float rden = dacc[h] > 0.f ? 1.0f / dacc[h] : 0.f;
    v += facc[h] * rden;
  }
  v = (v + sb) * 0.125f;
  out[(size_t)r * FO + lane] = v > 0.f ? v : 0.f;
}

extern "C" void kernel_launch(void* const* d_in, const int* in_sizes, int n_in,
                              void* d_out, int out_size, void* d_ws, size_t ws_size,
                              hipStream_t stream) {
  const float* x    = (const float*)d_in[0];
  const float* W    = (const float*)d_in[1];
  const float* a    = (const float*)d_in[2];
  const float* b    = (const float*)d_in[3];
  const int*   rows = (const int*)d_in[4];
  const int*   cols = (const int*)d_in[5];
  const int N = in_sizes[0] / FI;
  const int E = in_sizes[4];

  char* p = (char*)d_ws;
  _Float16* Th       = (_Float16*)p;  p += (size_t)N * FC * sizeof(_Float16);
  _Float16* Th2      = (_Float16*)p;  p += (size_t)N * FC * sizeof(_Float16);
  _Float16* Wth      = (_Float16*)p;  p += (size_t)NH * FO * FI * sizeof(_Float16);
  float*    aw       = (float*)p;     p += (size_t)N * NH * sizeof(float);
  int*      deg      = (int*)p;       p += (size_t)N * sizeof(int);
  int*      row_start= (int*)p;       p += (size_t)(N + 4) * sizeof(int);
  int*      cursor   = (int*)p;       p += (size_t)N * sizeof(int);
  int*      colperm  = (int*)p;       p += (size_t)E * sizeof(int);
  int*      blocksums= (int*)p;       p += 64 * sizeof(int);
  float*    out = (float*)d_out;

  const int nb = (N + 1023) / 1024;

  // CSR build
  hipMemsetAsync(deg, 0, (size_t)N * sizeof(int), stream);
  b1_hist<<<(E + 255) / 256, 256, 0, stream>>>(rows, deg, E);
  b2a_blocksum<<<nb, 256, 0, stream>>>(deg, blocksums, N);
  b2b_scanblocks<<<1, 64, 0, stream>>>(blocksums, nb, row_start, N, E);
  b2c_rescan<<<nb, 256, 0, stream>>>(deg, blocksums, row_start, cursor, N);
  b3_scatter<<<(E + 255) / 256, 256, 0, stream>>>(rows, cols, cursor, colperm, E);

  // dense feature transform
  p1_wconv<<<(NH * FO * FI + 255) / 256, 256, 0, stream>>>(W, Wth);
  k1_mfma<<<dim3((N + 63) / 64, NH), 256, 0, stream>>>(x, Wth, Th, N);
  k2t<<<N, 512, 0, stream>>>(Th, a, aw, Th2, N);

  // fused edge pipeline
  k4_fused<<<(N + 3) / 4, 256, 0, stream>>>(row_start, colperm, aw, Th2, b, out, N);
}

// Round 6
// 314.644 us; speedup vs baseline: 1.1777x; 1.1777x over previous
//
#include <hip/hip_runtime.h>
#include <hip/hip_bf16.h>

// SparseGAT forward. fp16-MFMA feature transform (all heads per block, fused
// transpose + aw); CSR edge pipeline with row-per-16-lane-group aggregation.
// N=50000, FI=256, FO=64, H=8, E=800000. avg deg = 16.
//
// Th2 [n][f*8+h] head-minor fp16: one b128 per 16-lane group reads a
// quarter (128 f16) of a node's 512-value feature row.
//
// ws: Th2[N*512]f16 | Wth[8*64*256]f16 | aw[N*8]f32 | deg[N] | row_start[N+4]
//     | cursor[N] | colperm[E] | blocksums[64]

#define FI 256
#define FO 64
#define NH 8
#define FC (NH * FO)  // 512
#define TTP 528       // Tt row stride (f16): 512 + 16 pad (16B-aligned rows)

typedef _Float16 f16x8 __attribute__((ext_vector_type(8)));
typedef float f32x16 __attribute__((ext_vector_type(16)));
typedef float f32x8 __attribute__((ext_vector_type(8)));

// ---------------- P1: W[h][k][f] -> Wth[h][f][k] fp16 -----------------------
__global__ __launch_bounds__(256)
void p1_wconv(const float* __restrict__ W, _Float16* __restrict__ Wth) {
  int idx = blockIdx.x * 256 + threadIdx.x;   // h*64*256 + f*256 + k
  if (idx >= NH * FO * FI) return;
  int k = idx & (FI - 1);
  int f = (idx >> 8) & (FO - 1);
  int h = idx >> 14;
  Wth[idx] = (_Float16)W[((size_t)h * FI + k) * FO + f];
}

// ---------------- K1: all-head MFMA + transpose + aw ------------------------
// grid ceil(N/32), 256 threads = 4 waves. Wave w computes heads {2w, 2w+1}.
// Outputs: Th2[n][f*8+h] fp16, aw[n][h] f32.
__global__ __launch_bounds__(256)
void k1_fused(const float* __restrict__ x, const _Float16* __restrict__ Wth,
              const float* __restrict__ a, _Float16* __restrict__ Th2,
              float* __restrict__ aw, int N) {
  __shared__ _Float16 Xs[32][264];
  __shared__ _Float16 Tt[32][TTP];
  const int bm  = blockIdx.x * 32;
  const int t   = threadIdx.x;
  const int lane = t & 63;
  const int wid  = t >> 6;
  const int l31 = lane & 31;
  const int kh  = (lane >> 5) * 8;

  // stage 32x256 x-tile: fp32 float4 -> fp16, 8B LDS stores
  #pragma unroll
  for (int r = 0; r < 8; ++r) {
    int i = t + r * 256;            // float4 chunk 0..2047
    int row = i >> 6;               // 64 float4 per row
    int q   = i & 63;
    int grow = bm + row;
    float4 v = make_float4(0.f, 0.f, 0.f, 0.f);
    if (grow < N)
      v = reinterpret_cast<const float4*>(&x[(size_t)grow * FI])[q];
    _Float16 o[4] = {(_Float16)v.x, (_Float16)v.y, (_Float16)v.z, (_Float16)v.w};
    *reinterpret_cast<uint2*>(&Xs[row][q * 4]) = *reinterpret_cast<uint2*>(o);
  }
  __syncthreads();

  // MFMA: 2 heads x 2 col-halves per wave, K=256
  #pragma unroll
  for (int hh = 0; hh < 2; ++hh) {
    const int h = wid * 2 + hh;
    #pragma unroll
    for (int wc = 0; wc < 2; ++wc) {
      const _Float16* Wcol = Wth + ((size_t)h * FO + wc * 32 + l31) * FI;
      f32x16 acc = (f32x16)0.0f;
      #pragma unroll
      for (int kk = 0; kk < 16; ++kk) {
        f16x8 af = *reinterpret_cast<const f16x8*>(&Xs[l31][kk * 16 + kh]);
        f16x8 bf = *reinterpret_cast<const f16x8*>(&Wcol[kk * 16 + kh]);
        acc = __builtin_amdgcn_mfma_f32_32x32x16_f16(af, bf, acc, 0, 0, 0);
      }
      // C/D: col=lane&31, row=(reg&3)+8*(reg>>2)+4*(lane>>5); transpose to Tt
      const int f = wc * 32 + l31;
      #pragma unroll
      for (int reg = 0; reg < 16; ++reg) {
        int rr = (reg & 3) + 8 * (reg >> 2) + 4 * (lane >> 5);
        Tt[rr][f * NH + h] = (_Float16)acc[reg];
      }
    }
  }
  __syncthreads();

  // aw: wave w reduces rows [w*8, w*8+8); lane = feature f
  float a_l[NH];
  #pragma unroll
  for (int h = 0; h < NH; ++h) a_l[h] = a[h * FO + lane];
  #pragma unroll
  for (int rr = 0; rr < 8; ++rr) {
    const int row = wid * 8 + rr;
    f16x8 v = *reinterpret_cast<const f16x8*>(&Tt[row][lane * NH]);
    float p[NH];
    #pragma unroll
    for (int h = 0; h < NH; ++h) p[h] = (float)v[h] * a_l[h];
    #pragma unroll
    for (int off = 1; off < 64; off <<= 1) {
      #pragma unroll
      for (int h = 0; h < NH; ++h) p[h] += __shfl_xor(p[h], off);
    }
    if (lane == 0 && bm + row < N) {
      f32x8 o;
      #pragma unroll
      for (int h = 0; h < NH; ++h) o[h] = p[h];
      *reinterpret_cast<f32x8*>(&aw[(size_t)(bm + row) * NH]) = o;
    }
  }

  // copy-out Tt -> Th2 (coalesced uint4)
  #pragma unroll
  for (int r = 0; r < 8; ++r) {
    int i = t + r * 256;            // uint4 chunk 0..2047
    int row = i >> 6;               // 64 uint4 per row
    int q   = i & 63;
    if (bm + row < N)
      reinterpret_cast<uint4*>(&Th2[(size_t)(bm + row) * FC])[q] =
          *reinterpret_cast<const uint4*>(&Tt[row][q * 8]);
  }
}

// ---------------- B1: degree histogram --------------------------------------
__global__ __launch_bounds__(256)
void b1_hist(const int* __restrict__ rows, int* __restrict__ deg, int E) {
  int e = blockIdx.x * 256 + threadIdx.x;
  if (e < E) atomicAdd(&deg[rows[e]], 1);
}

// ---------------- B2a: per-block sums (1024 elems/block) --------------------
__global__ __launch_bounds__(256)
void b2a_blocksum(const int* __restrict__ deg, int* __restrict__ blocksums, int N) {
  __shared__ int red[256];
  const int t = threadIdx.x;
  const int base = blockIdx.x * 1024 + t * 4;
  int s = 0;
  #pragma unroll
  for (int j = 0; j < 4; ++j) { int i = base + j; if (i < N) s += deg[i]; }
  red[t] = s;
  __syncthreads();
  for (int off = 128; off; off >>= 1) {
    if (t < off) red[t] += red[t + off];
    __syncthreads();
  }
  if (t == 0) blocksums[blockIdx.x] = red[0];
}

// ---------------- B2b: exclusive scan of block sums (1 wave) ----------------
__global__ __launch_bounds__(64)
void b2b_scanblocks(int* __restrict__ blocksums, int nb,
                    int* __restrict__ row_start, int N, int E) {
  const int lane = threadIdx.x;
  int carry = 0;
  for (int base = 0; base < nb; base += 64) {
    int i = base + lane;
    int v = (i < nb) ? blocksums[i] : 0;
    int inc = v;
    #pragma unroll
    for (int off = 1; off < 64; off <<= 1) {
      int t = __shfl_up(inc, off);
      if (lane >= off) inc += t;
    }
    if (i < nb) blocksums[i] = inc - v + carry;  // exclusive
    carry += __shfl(inc, 63);
  }
  if (lane == 0) row_start[N] = E;
}

// ---------------- B2c: per-block rescan -> row_start, cursor ----------------
__global__ __launch_bounds__(256)
void b2c_rescan(const int* __restrict__ deg, const int* __restrict__ blocksums,
                int* __restrict__ row_start, int* __restrict__ cursor, int N) {
  __shared__ int ts[256];
  const int t = threadIdx.x;
  const int base = blockIdx.x * 1024 + t * 4;
  int v[4]; int s = 0;
  #pragma unroll
  for (int j = 0; j < 4; ++j) { int i = base + j; v[j] = (i < N) ? deg[i] : 0; s += v[j]; }
  ts[t] = s;
  __syncthreads();
  for (int off = 1; off < 256; off <<= 1) {
    int add = (t >= off) ? ts[t - off] : 0;
    __syncthreads();
    ts[t] += add;
    __syncthreads();
  }
  int run = blocksums[blockIdx.x] + ts[t] - s;
  #pragma unroll
  for (int j = 0; j < 4; ++j) {
    int i = base + j;
    if (i < N) { row_start[i] = run; cursor[i] = run; run += v[j]; }
  }
}

// ---------------- B3: scatter cols into CSR order ---------------------------
__global__ __launch_bounds__(256)
void b3_scatter(const int* __restrict__ rows, const int* __restrict__ cols,
                int* __restrict__ cursor, int* __restrict__ colperm, int E) {
  int e = blockIdx.x * 256 + threadIdx.x;
  if (e >= E) return;
  int pos = atomicAdd(&cursor[rows[e]], 1);
  colperm[pos] = cols[e];
}

// ---------------- K4: fused softmax + aggregation, row per 16-lane group ----
// 256 threads = 4 waves = 16 groups; group g owns row blk*16+g.
// Each group: softmax over <=16 edges lane-parallel; serial gather of
// 4 quarter-row b128 loads per edge (4 groups in lockstep per wave).
__global__ __launch_bounds__(256)
void k4_fused(const int* __restrict__ row_start, const int* __restrict__ colperm,
              const float* __restrict__ aw, const _Float16* __restrict__ Th2,
              const float* __restrict__ b, float* __restrict__ out, int N) {
  const int lane16 = threadIdx.x & 15;
  const int gbase  = threadIdx.x & 48;       // group base lane within wave
  const int r = blockIdx.x * 16 + (threadIdx.x >> 4);
  if (r >= N) return;

  const int s0 = row_start[r], s1 = row_start[r + 1];

  f32x8 awr = *reinterpret_cast<const f32x8*>(&aw[(size_t)r * NH]);

  float facc[4][NH] = {};
  float dacc[NH] = {};

  for (int base = s0; base < s1; base += 16) {
    const int mm = min(16, s1 - base);
    const bool valid = lane16 < mm;
    int c_l = valid ? colperm[base + lane16] : 0;

    // lane-parallel ex over this group's <=16 edges
    f32x8 awc = *reinterpret_cast<const f32x8*>(&aw[(size_t)c_l * NH]);
    float ex[NH];
    #pragma unroll
    for (int h = 0; h < NH; ++h) {
      float s = awr[h] + awc[h];
      float lr = s > 0.f ? s : 0.2f * s;
      ex[h] = valid ? __expf(lr) : 0.f;
      dacc[h] += ex[h];
    }

    // serial gather: per edge, 4 independent quarter-row loads
    for (int j = 0; j < mm; ++j) {
      int cj = __shfl(c_l, gbase + j);
      const _Float16* tp = Th2 + (size_t)cj * FC + lane16 * NH;
      f16x8 tv0 = *reinterpret_cast<const f16x8*>(tp);
      f16x8 tv1 = *reinterpret_cast<const f16x8*>(tp + 128);
      f16x8 tv2 = *reinterpret_cast<const f16x8*>(tp + 256);
      f16x8 tv3 = *reinterpret_cast<const f16x8*>(tp + 384);
      #pragma unroll
      for (int h = 0; h < NH; ++h) {
        float e = __shfl(ex[h], gbase + j);
        facc[0][h] = fmaf(e, (float)tv0[h], facc[0][h]);
        facc[1][h] = fmaf(e, (float)tv1[h], facc[1][h]);
        facc[2][h] = fmaf(e, (float)tv2[h], facc[2][h]);
        facc[3][h] = fmaf(e, (float)tv3[h], facc[3][h]);
      }
    }
  }

  // reduce den across the 16-lane group
  #pragma unroll
  for (int h = 0; h < NH; ++h) {
    #pragma unroll
    for (int off = 1; off < 16; off <<= 1)
      dacc[h] += __shfl_xor(dacc[h], off);
  }

  float rden[NH];
  #pragma unroll
  for (int h = 0; h < NH; ++h) rden[h] = dacc[h] > 0.f ? 1.0f / dacc[h] : 0.f;

  // combine heads, add bias, relu; lane16 covers f = q*16 + lane16
  #pragma unroll
  for (int q = 0; q < 4; ++q) {
    const int f = q * 16 + lane16;
    float sb = 0.f;
    #pragma unroll
    for (int h = 0; h < NH; ++h) sb += b[h * FO + f];
    float v = 0.f;
    #pragma unroll
    for (int h = 0; h < NH; ++h) v += facc[q][h] * rden[h];
    v = (v + sb) * 0.125f;
    out[(size_t)r * FO + f] = v > 0.f ? v : 0.f;
  }
}

extern "C" void kernel_launch(void* const* d_in, const int* in_sizes, int n_in,
                              void* d_out, int out_size, void* d_ws, size_t ws_size,
                              hipStream_t stream) {
  const float* x    = (const float*)d_in[0];
  const float* W    = (const float*)d_in[1];
  const float* a    = (const float*)d_in[2];
  const float* b    = (const float*)d_in[3];
  const int*   rows = (const int*)d_in[4];
  const int*   cols = (const int*)d_in[5];
  const int N = in_sizes[0] / FI;
  const int E = in_sizes[4];

  char* p = (char*)d_ws;
  _Float16* Th2      = (_Float16*)p;  p += (size_t)N * FC * sizeof(_Float16);
  _Float16* Wth      = (_Float16*)p;  p += (size_t)NH * FO * FI * sizeof(_Float16);
  float*    aw       = (float*)p;     p += (size_t)N * NH * sizeof(float);
  int*      deg      = (int*)p;       p += (size_t)N * sizeof(int);
  int*      row_start= (int*)p;       p += (size_t)(N + 4) * sizeof(int);
  int*      cursor   = (int*)p;       p += (size_t)N * sizeof(int);
  int*      colperm  = (int*)p;       p += (size_t)E * sizeof(int);
  int*      blocksums= (int*)p;       p += 64 * sizeof(int);
  float*    out = (float*)d_out;

  const int nb = (N + 1023) / 1024;

  // CSR build
  hipMemsetAsync(deg, 0, (size_t)N * sizeof(int), stream);
  b1_hist<<<(E + 255) / 256, 256, 0, stream>>>(rows, deg, E);
  b2a_blocksum<<<nb, 256, 0, stream>>>(deg, blocksums, N);
  b2b_scanblocks<<<1, 64, 0, stream>>>(blocksums, nb, row_start, N, E);
  b2c_rescan<<<nb, 256, 0, stream>>>(deg, blocksums, row_start, cursor, N);
  b3_scatter<<<(E + 255) / 256, 256, 0, stream>>>(rows, cols, cursor, colperm, E);

  // dense feature transform (all heads, fused transpose + aw)
  p1_wconv<<<(NH * FO * FI + 255) / 256, 256, 0, stream>>>(W, Wth);
  k1_fused<<<(N + 31) / 32, 256, 0, stream>>>(x, Wth, a, Th2, aw, N);

  // fused edge pipeline
  k4_fused<<<(N + 15) / 16, 256, 0, stream>>>(row_start, colperm, aw, Th2, b, out, N);
}

// Round 7
// 292.583 us; speedup vs baseline: 1.2665x; 1.0754x over previous
//
#include <hip/hip_runtime.h>
#include <hip/hip_bf16.h>

// SparseGAT forward. fp16-MFMA feature transform (128-row tile, wave-per-head,
// fused transpose + aw); CSR edge pipeline, 16-lane-group rows, LDS ex-stash,
// 2-deep pipelined gather. N=50000, FI=256, FO=64, H=8, E=800000, avg deg 16.
//
// Th2 [n][f*8+h] head-minor fp16 (1KB/row).
// ws: Th2[N*512]f16 | Wth[8*64*256]f16 | aw[N*8]f32 | deg[N] | row_start[N+4]
//     | cursor[N] | colperm[E] | blocksums[64]

#define FI 256
#define FO 64
#define NH 8
#define FC 512
#define BM 128

typedef _Float16 f16x8 __attribute__((ext_vector_type(8)));
typedef float f32x16 __attribute__((ext_vector_type(16)));
typedef float f32x8 __attribute__((ext_vector_type(8)));
typedef float f32x4 __attribute__((ext_vector_type(4)));

// ---------------- P1: W[h][k][f] -> Wth[h][f][k] fp16 -----------------------
__global__ __launch_bounds__(256)
void p1_wconv(const float* __restrict__ W, _Float16* __restrict__ Wth) {
  int idx = blockIdx.x * 256 + threadIdx.x;   // h*64*256 + f*256 + k
  if (idx >= NH * FO * FI) return;
  int k = idx & (FI - 1);
  int f = (idx >> 8) & (FO - 1);
  int h = idx >> 14;
  Wth[idx] = (_Float16)W[((size_t)h * FI + k) * FO + f];
}

// ---------------- K1v2: 128-row tile, wave = head ---------------------------
// 512 threads = 8 waves; wave w computes head w for 128 rows (4 x 32x32 MFMA
// row-tiles x 2 col-halves), K in 2 chunks of 128 staged in LDS.
// Epilogue: aw via shfl-reduce; Th2 via 4x 32-row LDS transpose chunks.
__global__ __launch_bounds__(512)
void k1_v2(const float* __restrict__ x, const _Float16* __restrict__ Wth,
           const float* __restrict__ a, _Float16* __restrict__ Th2,
           float* __restrict__ aw, int N) {
  __shared__ _Float16 smem[BM * 136];            // 34.8 KB, aliased Xs / Tt
  auto Xs = reinterpret_cast<_Float16(*)[136]>(smem);   // [128][136]
  auto Tt = reinterpret_cast<_Float16(*)[512]>(smem);   // [32][512]
  const int bm = blockIdx.x * BM;
  const int t = threadIdx.x;
  const int w = t >> 6;             // wave id = head
  const int lane = t & 63;
  const int l31 = lane & 31;
  const int kh = (lane >> 5) * 8;
  const _Float16* Wh = Wth + (size_t)w * (FO * FI);

  f32x16 acc[4][2];
  #pragma unroll
  for (int mr = 0; mr < 4; ++mr)
    #pragma unroll
    for (int wc = 0; wc < 2; ++wc) acc[mr][wc] = (f32x16)0.0f;

  #pragma unroll
  for (int k0 = 0; k0 < 2; ++k0) {
    if (k0) __syncthreads();
    // stage 128x128 fp16 chunk: 128 rows x 32 float4 -> fp16
    #pragma unroll
    for (int r = 0; r < 8; ++r) {
      int i = t + r * 512;          // 0..4095
      int row = i >> 5;             // 32 float4 per row
      int q = i & 31;
      float4 v = make_float4(0.f, 0.f, 0.f, 0.f);
      if (bm + row < N)
        v = reinterpret_cast<const float4*>(&x[(size_t)(bm + row) * FI + k0 * 128])[q];
      _Float16 o[4] = {(_Float16)v.x, (_Float16)v.y, (_Float16)v.z, (_Float16)v.w};
      *reinterpret_cast<uint2*>(&Xs[row][q * 4]) = *reinterpret_cast<uint2*>(o);
    }
    __syncthreads();
    #pragma unroll
    for (int kk = 0; kk < 8; ++kk) {
      f16x8 af[4], bf[2];
      #pragma unroll
      for (int mr = 0; mr < 4; ++mr)
        af[mr] = *reinterpret_cast<const f16x8*>(&Xs[mr * 32 + l31][kk * 16 + kh]);
      #pragma unroll
      for (int wc = 0; wc < 2; ++wc)
        bf[wc] = *reinterpret_cast<const f16x8*>(
            &Wh[(size_t)(wc * 32 + l31) * FI + k0 * 128 + kk * 16 + kh]);
      #pragma unroll
      for (int mr = 0; mr < 4; ++mr)
        #pragma unroll
        for (int wc = 0; wc < 2; ++wc)
          acc[mr][wc] =
              __builtin_amdgcn_mfma_f32_32x32x16_f16(af[mr], bf[wc], acc[mr][wc], 0, 0, 0);
    }
  }

  // aw[n][w] = sum_f T[n][w][f] * a[w][f]  (reduce across the 32 l31 lanes)
  const float av0 = a[w * FO + l31], av1 = a[w * FO + 32 + l31];
  #pragma unroll
  for (int mr = 0; mr < 4; ++mr)
    #pragma unroll
    for (int reg = 0; reg < 16; ++reg) {
      float s = acc[mr][0][reg] * av0 + acc[mr][1][reg] * av1;
      #pragma unroll
      for (int off = 1; off < 32; off <<= 1) s += __shfl_xor(s, off);
      if (l31 == 0) {
        int rl = mr * 32 + (reg & 3) + 8 * (reg >> 2) + 4 * (lane >> 5);
        if (bm + rl < N) aw[(size_t)(bm + rl) * NH + w] = s;
      }
    }

  // Th2: transpose 32-row chunks through LDS, coalesced 16B stores
  #pragma unroll
  for (int ch = 0; ch < 4; ++ch) {
    __syncthreads();
    #pragma unroll
    for (int wc = 0; wc < 2; ++wc) {
      const int f = wc * 32 + l31;
      #pragma unroll
      for (int reg = 0; reg < 16; ++reg) {
        int rl = (reg & 3) + 8 * (reg >> 2) + 4 * (lane >> 5);
        Tt[rl][f * NH + w] = (_Float16)acc[ch][wc][reg];
      }
    }
    __syncthreads();
    #pragma unroll
    for (int r = 0; r < 4; ++r) {
      int i = t + r * 512;          // 0..2047
      int row = i >> 6, q = i & 63;
      int grow = bm + ch * 32 + row;
      if (grow < N)
        *reinterpret_cast<uint4*>(&Th2[(size_t)grow * FC + q * 8]) =
            *reinterpret_cast<const uint4*>(&Tt[row][q * 8]);
    }
  }
}

// ---------------- B1: degree histogram --------------------------------------
__global__ __launch_bounds__(256)
void b1_hist(const int* __restrict__ rows, int* __restrict__ deg, int E) {
  int e = blockIdx.x * 256 + threadIdx.x;
  if (e < E) atomicAdd(&deg[rows[e]], 1);
}

// ---------------- B2a: per-block sums (1024 elems/block) --------------------
__global__ __launch_bounds__(256)
void b2a_blocksum(const int* __restrict__ deg, int* __restrict__ blocksums, int N) {
  __shared__ int red[256];
  const int t = threadIdx.x;
  const int base = blockIdx.x * 1024 + t * 4;
  int s = 0;
  #pragma unroll
  for (int j = 0; j < 4; ++j) { int i = base + j; if (i < N) s += deg[i]; }
  red[t] = s;
  __syncthreads();
  for (int off = 128; off; off >>= 1) {
    if (t < off) red[t] += red[t + off];
    __syncthreads();
  }
  if (t == 0) blocksums[blockIdx.x] = red[0];
}

// ---------------- B2b: exclusive scan of block sums (1 wave) ----------------
__global__ __launch_bounds__(64)
void b2b_scanblocks(int* __restrict__ blocksums, int nb,
                    int* __restrict__ row_start, int N, int E) {
  const int lane = threadIdx.x;
  int carry = 0;
  for (int base = 0; base < nb; base += 64) {
    int i = base + lane;
    int v = (i < nb) ? blocksums[i] : 0;
    int inc = v;
    #pragma unroll
    for (int off = 1; off < 64; off <<= 1) {
      int t = __shfl_up(inc, off);
      if (lane >= off) inc += t;
    }
    if (i < nb) blocksums[i] = inc - v + carry;  // exclusive
    carry += __shfl(inc, 63);
  }
  if (lane == 0) row_start[N] = E;
}

// ---------------- B2c: per-block rescan -> row_start, cursor ----------------
__global__ __launch_bounds__(256)
void b2c_rescan(const int* __restrict__ deg, const int* __restrict__ blocksums,
                int* __restrict__ row_start, int* __restrict__ cursor, int N) {
  __shared__ int ts[256];
  const int t = threadIdx.x;
  const int base = blockIdx.x * 1024 + t * 4;
  int v[4]; int s = 0;
  #pragma unroll
  for (int j = 0; j < 4; ++j) { int i = base + j; v[j] = (i < N) ? deg[i] : 0; s += v[j]; }
  ts[t] = s;
  __syncthreads();
  for (int off = 1; off < 256; off <<= 1) {
    int add = (t >= off) ? ts[t - off] : 0;
    __syncthreads();
    ts[t] += add;
    __syncthreads();
  }
  int run = blocksums[blockIdx.x] + ts[t] - s;
  #pragma unroll
  for (int j = 0; j < 4; ++j) {
    int i = base + j;
    if (i < N) { row_start[i] = run; cursor[i] = run; run += v[j]; }
  }
}

// ---------------- B3: scatter cols into CSR order ---------------------------
__global__ __launch_bounds__(256)
void b3_scatter(const int* __restrict__ rows, const int* __restrict__ cols,
                int* __restrict__ cursor, int* __restrict__ colperm, int E) {
  int e = blockIdx.x * 256 + threadIdx.x;
  if (e >= E) return;
  int pos = atomicAdd(&cursor[rows[e]], 1);
  colperm[pos] = cols[e];
}

// ---------------- K4: fused softmax + aggregation, row per 16-lane group ----
// LDS ex-stash replaces 8 shfl-broadcasts/edge; gather 2-deep pipelined.
__global__ __launch_bounds__(256)
void k4_fused(const int* __restrict__ row_start, const int* __restrict__ colperm,
              const float* __restrict__ aw, const _Float16* __restrict__ Th2,
              const float* __restrict__ b, float* __restrict__ out, int N) {
  __shared__ float exs[16][132];   // [group][j*8+h]; stride 132: 16B-aligned rows
  const int lane16 = threadIdx.x & 15;
  const int g      = threadIdx.x >> 4;       // 0..15
  const int gbase  = threadIdx.x & 48;       // group base lane within wave
  const int r = blockIdx.x * 16 + g;
  if (r >= N) return;
  float* exg = &exs[g][0];

  const int s0 = row_start[r], s1 = row_start[r + 1];
  f32x8 awr = *reinterpret_cast<const f32x8*>(&aw[(size_t)r * NH]);

  float facc[4][NH] = {};
  float dacc[NH] = {};

  for (int base = s0; base < s1; base += 16) {
    const int mm = min(16, s1 - base);
    const bool valid = lane16 < mm;
    int c_l = valid ? colperm[base + lane16] : 0;

    f32x8 awc = *reinterpret_cast<const f32x8*>(&aw[(size_t)c_l * NH]);
    #pragma unroll
    for (int h = 0; h < NH; ++h) {
      float s = awr[h] + awc[h];
      float lr = s > 0.f ? s : 0.2f * s;
      float e = valid ? __expf(lr) : 0.f;
      dacc[h] += e;
      exg[lane16 * NH + h] = e;   // wave-internal LDS, no barrier needed
    }

    // 2-deep pipelined gather: edge j's FMAs overlap edge j+1's loads
    int cj = __shfl(c_l, gbase);
    const _Float16* tp = Th2 + (size_t)cj * FC + lane16 * NH;
    f16x8 A0 = *reinterpret_cast<const f16x8*>(tp);
    f16x8 A1 = *reinterpret_cast<const f16x8*>(tp + 128);
    f16x8 A2 = *reinterpret_cast<const f16x8*>(tp + 256);
    f16x8 A3 = *reinterpret_cast<const f16x8*>(tp + 384);
    for (int j = 0; j < mm; ++j) {
      f16x8 B0, B1, B2, B3;
      if (j + 1 < mm) {
        int cn = __shfl(c_l, gbase + j + 1);
        const _Float16* tq = Th2 + (size_t)cn * FC + lane16 * NH;
        B0 = *reinterpret_cast<const f16x8*>(tq);
        B1 = *reinterpret_cast<const f16x8*>(tq + 128);
        B2 = *reinterpret_cast<const f16x8*>(tq + 256);
        B3 = *reinterpret_cast<const f16x8*>(tq + 384);
      }
      f32x4 e0 = *reinterpret_cast<const f32x4*>(&exg[j * NH]);
      f32x4 e1 = *reinterpret_cast<const f32x4*>(&exg[j * NH + 4]);
      #pragma unroll
      for (int h = 0; h < 4; ++h) {
        facc[0][h]     = fmaf(e0[h], (float)A0[h],     facc[0][h]);
        facc[1][h]     = fmaf(e0[h], (float)A1[h],     facc[1][h]);
        facc[2][h]     = fmaf(e0[h], (float)A2[h],     facc[2][h]);
        facc[3][h]     = fmaf(e0[h], (float)A3[h],     facc[3][h]);
        facc[0][h + 4] = fmaf(e1[h], (float)A0[h + 4], facc[0][h + 4]);
        facc[1][h + 4] = fmaf(e1[h], (float)A1[h + 4], facc[1][h + 4]);
        facc[2][h + 4] = fmaf(e1[h], (float)A2[h + 4], facc[2][h + 4]);
        facc[3][h + 4] = fmaf(e1[h], (float)A3[h + 4], facc[3][h + 4]);
      }
      A0 = B0; A1 = B1; A2 = B2; A3 = B3;
    }
  }

  #pragma unroll
  for (int h = 0; h < NH; ++h) {
    #pragma unroll
    for (int off = 1; off < 16; off <<= 1)
      dacc[h] += __shfl_xor(dacc[h], off);
  }

  float rden[NH];
  #pragma unroll
  for (int h = 0; h < NH; ++h) rden[h] = dacc[h] > 0.f ? 1.0f / dacc[h] : 0.f;

  #pragma unroll
  for (int q = 0; q < 4; ++q) {
    const int f = q * 16 + lane16;
    float sb = 0.f;
    #pragma unroll
    for (int h = 0; h < NH; ++h) sb += b[h * FO + f];
    float v = 0.f;
    #pragma unroll
    for (int h = 0; h < NH; ++h) v += facc[q][h] * rden[h];
    v = (v + sb) * 0.125f;
    out[(size_t)r * FO + f] = v > 0.f ? v : 0.f;
  }
}

extern "C" void kernel_launch(void* const* d_in, const int* in_sizes, int n_in,
                              void* d_out, int out_size, void* d_ws, size_t ws_size,
                              hipStream_t stream) {
  const float* x    = (const float*)d_in[0];
  const float* W    = (const float*)d_in[1];
  const float* a    = (const float*)d_in[2];
  const float* b    = (const float*)d_in[3];
  const int*   rows = (const int*)d_in[4];
  const int*   cols = (const int*)d_in[5];
  const int N = in_sizes[0] / FI;
  const int E = in_sizes[4];

  char* p = (char*)d_ws;
  _Float16* Th2      = (_Float16*)p;  p += (size_t)N * FC * sizeof(_Float16);
  _Float16* Wth      = (_Float16*)p;  p += (size_t)NH * FO * FI * sizeof(_Float16);
  float*    aw       = (float*)p;     p += (size_t)N * NH * sizeof(float);
  int*      deg      = (int*)p;       p += (size_t)N * sizeof(int);
  int*      row_start= (int*)p;       p += (size_t)(N + 4) * sizeof(int);
  int*      cursor   = (int*)p;       p += (size_t)N * sizeof(int);
  int*      colperm  = (int*)p;       p += (size_t)E * sizeof(int);
  int*      blocksums= (int*)p;       p += 64 * sizeof(int);
  float*    out = (float*)d_out;

  const int nb = (N + 1023) / 1024;

  // CSR build
  hipMemsetAsync(deg, 0, (size_t)N * sizeof(int), stream);
  b1_hist<<<(E + 255) / 256, 256, 0, stream>>>(rows, deg, E);
  b2a_blocksum<<<nb, 256, 0, stream>>>(deg, blocksums, N);
  b2b_scanblocks<<<1, 64, 0, stream>>>(blocksums, nb, row_start, N, E);
  b2c_rescan<<<nb, 256, 0, stream>>>(deg, blocksums, row_start, cursor, N);
  b3_scatter<<<(E + 255) / 256, 256, 0, stream>>>(rows, cols, cursor, colperm, E);

  // dense feature transform (all heads, fused transpose + aw)
  p1_wconv<<<(NH * FO * FI + 255) / 256, 256, 0, stream>>>(W, Wth);
  k1_v2<<<(N + BM - 1) / BM, 512, 0, stream>>>(x, Wth, a, Th2, aw, N);

  // fused edge pipeline
  k4_fused<<<(N + 15) / 16, 256, 0, stream>>>(row_start, colperm, aw, Th2, b, out, N);
}